// Round 6
// baseline (140.195 us; speedup 1.0000x reference)
//
#include <hip/hip_runtime.h>
#include <math.h>

#define NHEAD 4
#define DHEAD 32
#define NPIX  4096
#define CIN   128

typedef __bf16 bf16_t;
typedef __bf16 bf16x8 __attribute__((ext_vector_type(8)));
typedef __bf16 bf16x4 __attribute__((ext_vector_type(4)));
typedef float  f32x4  __attribute__((ext_vector_type(4)));

// 1/sqrt(32) * log2(e): folded into q weights so softmax exp is bare exp2.
constexpr float QSCALE = 0.17677669529663687f * 1.4426950408889634f;

// ---------------------------------------------------------------------------
// QKV projection, bf16 MFMA, weights cast f32->bf16 in-register. Wave cg
// owns 64 out-channels (0,1=q 2,3=k 4,5=v). x tile staged transposed to LDS
// [p][c] (stride 136). v waves swap mfma operand order -> pixel-major C ->
// packed b64 stores into vT[d][p]. grid (128 ptiles, 4 batch), block 384.
// ---------------------------------------------------------------------------
__global__ void __launch_bounds__(384) qkv_mfma(
    const float* __restrict__ x, const float* __restrict__ wqkv,
    ushort* __restrict__ qb, ushort* __restrict__ kb, ushort* __restrict__ vT) {
  __shared__ ushort Xls[32 * 136];
  const int tid = threadIdx.x, cg = tid >> 6, lane = tid & 63;
  const int n = lane & 15, quad = lane >> 4;
  const int b = blockIdx.y, p0 = blockIdx.x * 32;

  const float wsc = (cg < 2) ? QSCALE : 1.0f;
  bf16x8 wf[4][4];
#pragma unroll
  for (int t1 = 0; t1 < 4; ++t1)
#pragma unroll
    for (int k = 0; k < 4; ++k) {
      const float* wp = wqkv + (size_t)(cg * 64 + t1 * 16 + n) * CIN + k * 32 + quad * 8;
      float4 a = *(const float4*)wp;
      float4 c = *(const float4*)(wp + 4);
      wf[t1][k] = (bf16x8){(bf16_t)(a.x * wsc), (bf16_t)(a.y * wsc),
                           (bf16_t)(a.z * wsc), (bf16_t)(a.w * wsc),
                           (bf16_t)(c.x * wsc), (bf16_t)(c.y * wsc),
                           (bf16_t)(c.z * wsc), (bf16_t)(c.w * wsc)};
    }

  // stage x[b][c][p0..p0+31] -> Xls[p][c] (4x4 in-register transpose)
  if (tid < 256) {
    const int pc = tid & 7;
    const int c  = (tid >> 3) * 4;
    const float* xp = x + ((size_t)b * CIN + c) * NPIX + p0 + pc * 4;
    float4 r0 = *(const float4*)xp;
    float4 r1 = *(const float4*)(xp + NPIX);
    float4 r2 = *(const float4*)(xp + 2 * NPIX);
    float4 r3 = *(const float4*)(xp + 3 * NPIX);
    bf16x4 w0 = {(bf16_t)r0.x, (bf16_t)r1.x, (bf16_t)r2.x, (bf16_t)r3.x};
    bf16x4 w1 = {(bf16_t)r0.y, (bf16_t)r1.y, (bf16_t)r2.y, (bf16_t)r3.y};
    bf16x4 w2 = {(bf16_t)r0.z, (bf16_t)r1.z, (bf16_t)r2.z, (bf16_t)r3.z};
    bf16x4 w3 = {(bf16_t)r0.w, (bf16_t)r1.w, (bf16_t)r2.w, (bf16_t)r3.w};
    *(bf16x4*)&Xls[(pc * 4 + 0) * 136 + c] = w0;
    *(bf16x4*)&Xls[(pc * 4 + 1) * 136 + c] = w1;
    *(bf16x4*)&Xls[(pc * 4 + 2) * 136 + c] = w2;
    *(bf16x4*)&Xls[(pc * 4 + 3) * 136 + c] = w3;
  }
  __syncthreads();

  f32x4 acc[4][2];
#pragma unroll
  for (int i = 0; i < 4; ++i)
#pragma unroll
    for (int j = 0; j < 2; ++j) acc[i][j] = (f32x4){0.f, 0.f, 0.f, 0.f};

  const bool isv = (cg >= 4);
#pragma unroll
  for (int k = 0; k < 4; ++k) {
    bf16x8 xf[2];
#pragma unroll
    for (int pt = 0; pt < 2; ++pt)
      xf[pt] = *(const bf16x8*)&Xls[(pt * 16 + n) * 136 + k * 32 + quad * 8];
    if (!isv) {
#pragma unroll
      for (int wt = 0; wt < 4; ++wt)
#pragma unroll
        for (int pt = 0; pt < 2; ++pt)
          acc[wt][pt] = __builtin_amdgcn_mfma_f32_16x16x32_bf16(
              wf[wt][k], xf[pt], acc[wt][pt], 0, 0, 0);
    } else {
#pragma unroll
      for (int ct = 0; ct < 4; ++ct)
#pragma unroll
        for (int pt = 0; pt < 2; ++pt)
          acc[ct][pt] = __builtin_amdgcn_mfma_f32_16x16x32_bf16(
              xf[pt], wf[ct][k], acc[ct][pt], 0, 0, 0);
    }
  }

  if (!isv) {
    ushort* dst0 = (cg < 2) ? qb : kb;
#pragma unroll
    for (int wt = 0; wt < 4; ++wt) {
      const int ch = (cg & 1) * 64 + wt * 16 + quad * 4;
      const int head = ch >> 5, d = ch & 31;
#pragma unroll
      for (int pt = 0; pt < 2; ++pt) {
        const int p = p0 + pt * 16 + n;
        f32x4 a = acc[wt][pt];
        bf16x4 o = {(bf16_t)a[0], (bf16_t)a[1], (bf16_t)a[2], (bf16_t)a[3]};
        *(bf16x4*)(dst0 + ((size_t)(b * NHEAD + head) * NPIX + p) * DHEAD + d) = o;
      }
    }
  } else {
#pragma unroll
    for (int ct = 0; ct < 4; ++ct) {
      const int ch = (cg & 1) * 64 + ct * 16 + n;
      const int head = ch >> 5, d = ch & 31;
#pragma unroll
      for (int pt = 0; pt < 2; ++pt) {
        const int p = p0 + pt * 16 + quad * 4;
        f32x4 a = acc[ct][pt];
        bf16x4 o = {(bf16_t)a[0], (bf16_t)a[1], (bf16_t)a[2], (bf16_t)a[3]};
        *(bf16x4*)(vT + ((size_t)(b * NHEAD + head) * DHEAD + d) * NPIX + p) = o;
      }
    }
  }
}

// ---------------------------------------------------------------------------
// Flash attention v4: XCD-aware swizzle. 1-D grid of 1024 blocks; decode
//   xcd = id&7, bh = xcd*2 + ((id>>3)&1), qblock = id>>4.
// With blocks round-robined over 8 XCDs, each XCD serves exactly 2 bh ->
// 1 MB K/V working set, L2-resident (kills the ~900-cyc L2-miss stalls that
// capped round 5; FETCH was 34.8 MB vs 12 MB ideal).
// Block = 64 queries x 4 key-split waves, LDS-free main loop (permuted-key
// S^T trick: exp2 C-layout == PV A-layout), l via ones-MFMA, one-barrier
// LDS combine, normalized bf16 aoT out. block 256.
// ---------------------------------------------------------------------------
__device__ __forceinline__ void fl_load(const ushort* kb0, const ushort* vb0,
                                        int st, bf16x8* f) {
  f[0] = *(const bf16x8*)(kb0 + (size_t)(st * 32) * DHEAD);
  f[1] = *(const bf16x8*)(kb0 + (size_t)(st * 32 + 4) * DHEAD);
  f[2] = *(const bf16x8*)(vb0 + st * 32);
  f[3] = *(const bf16x8*)(vb0 + (size_t)16 * NPIX + st * 32);
}

__device__ __forceinline__ void fl_compute(const bf16x8* qf, const bf16x8* f,
                                           const bf16x8 ones,
                                           f32x4 O[4][2], f32x4* Ol) {
  const f32x4 zero = {0.f, 0.f, 0.f, 0.f};
#pragma unroll
  for (int rp = 0; rp < 4; ++rp) {
    f32x4 sa = __builtin_amdgcn_mfma_f32_16x16x32_bf16(f[0], qf[rp], zero, 0, 0, 0);
    f32x4 sb = __builtin_amdgcn_mfma_f32_16x16x32_bf16(f[1], qf[rp], zero, 0, 0, 0);
    bf16x8 pf;
#pragma unroll
    for (int r = 0; r < 4; ++r) {
      pf[r]     = (bf16_t)__builtin_amdgcn_exp2f(sa[r]);
      pf[r + 4] = (bf16_t)__builtin_amdgcn_exp2f(sb[r]);
    }
    O[rp][0] = __builtin_amdgcn_mfma_f32_16x16x32_bf16(pf, f[2], O[rp][0], 0, 0, 0);
    O[rp][1] = __builtin_amdgcn_mfma_f32_16x16x32_bf16(pf, f[3], O[rp][1], 0, 0, 0);
    Ol[rp]   = __builtin_amdgcn_mfma_f32_16x16x32_bf16(pf, ones, Ol[rp], 0, 0, 0);
  }
}

__global__ void __launch_bounds__(256, 4) flash_mfma(
    const ushort* __restrict__ qb, const ushort* __restrict__ kbuf,
    const ushort* __restrict__ vTb, ushort* __restrict__ aoT) {
  __shared__ float Ols[4][64][34];   // [wave][q][d 0..31, l at 32]
  const int tid = threadIdx.x, wave = tid >> 6, lane = tid & 63;
  const int n = lane & 15, quad = lane >> 4;
  const int id = blockIdx.x;
  const int bh = (id & 7) * 2 + ((id >> 3) & 1);   // XCD-locality decode
  const int q0 = (id >> 4) * 64;

  const ushort* kg = kbuf + (size_t)bh * NPIX * DHEAD;
  const ushort* vg = vTb + (size_t)bh * DHEAD * NPIX;

  bf16x8 qf[4];
#pragma unroll
  for (int rp = 0; rp < 4; ++rp)
    qf[rp] = *(const bf16x8*)(qb +
        ((size_t)bh * NPIX + q0 + rp * 16 + n) * DHEAD + quad * 8);

  f32x4 O[4][2], Ol[4];
#pragma unroll
  for (int rp = 0; rp < 4; ++rp) {
    O[rp][0] = (f32x4){0.f, 0.f, 0.f, 0.f};
    O[rp][1] = (f32x4){0.f, 0.f, 0.f, 0.f};
    Ol[rp]   = (f32x4){0.f, 0.f, 0.f, 0.f};
  }
  const bf16_t one = (bf16_t)1.0f;
  const bf16x8 ones = {one, one, one, one, one, one, one, one};

  // permuted K row pi(n) = (n>>2)*8 + (n&3): exp2 C-layout == PV A-layout
  const int pk = ((n >> 2) << 3) | (n & 3);
  const ushort* kb0 = kg + (size_t)(wave * 1024 + pk) * DHEAD + quad * 8;
  const ushort* vb0 = vg + (size_t)n * NPIX + wave * 1024 + quad * 8;

  bf16x8 fA[4], fB[4];
  fl_load(kb0, vb0, 0, fA);
#pragma unroll 1
  for (int st = 0; st < 32; st += 2) {
    fl_load(kb0, vb0, st + 1, fB);
    fl_compute(qf, fA, ones, O, Ol);
    if (st + 2 < 32) fl_load(kb0, vb0, st + 2, fA);
    fl_compute(qf, fB, ones, O, Ol);
  }

  // cross-wave combine in LDS (one barrier), write normalized bf16 aoT
  float* W = &Ols[wave][0][0];
#pragma unroll
  for (int rp = 0; rp < 4; ++rp)
#pragma unroll
    for (int r = 0; r < 4; ++r) {
      const int q = rp * 16 + quad * 4 + r;
      W[q * 34 + n]      = O[rp][0][r];
      W[q * 34 + 16 + n] = O[rp][1][r];
      if (n == 0) W[q * 34 + 32] = Ol[rp][r];
    }
  __syncthreads();

  const int q = tid >> 2, dg = tid & 3;
  const float l = Ols[0][q][32] + Ols[1][q][32] + Ols[2][q][32] + Ols[3][q][32];
  const float inv = 1.f / l;
  bf16x8 o8;
#pragma unroll
  for (int e = 0; e < 8; ++e) {
    const int d = dg * 8 + e;
    const float s = Ols[0][q][d] + Ols[1][q][d] + Ols[2][q][d] + Ols[3][q][d];
    o8[e] = (bf16_t)(s * inv);
  }
  *(bf16x8*)(aoT + ((size_t)bh * NPIX + q0 + q) * DHEAD + dg * 8) = o8;
}

// ---------------------------------------------------------------------------
// Output projection, bf16 MFMA, weights cast in-register. Block = 256
// (4 waves): wave = 16 px x 64 oc; 32-px tiles -> grid (128, 4) = 512 blocks
// (2 blocks/CU, 8 waves/CU vs 1 block/CU before).
// ---------------------------------------------------------------------------
__global__ void __launch_bounds__(256) out_mfma(
    const ushort* __restrict__ aoT, const float* __restrict__ wout,
    const float* __restrict__ bias, float* __restrict__ out) {
  const int tid = threadIdx.x, wv = tid >> 6, lane = tid & 63;
  const int n = lane & 15, quad = lane >> 4;
  const int b = blockIdx.y;
  const int oc0 = (wv & 1) * 64;
  const int p = blockIdx.x * 32 + (wv >> 1) * 16 + n;

  bf16x8 wf[4][4];
#pragma unroll
  for (int mt = 0; mt < 4; ++mt)
#pragma unroll
    for (int k = 0; k < 4; ++k) {
      const float* wp = wout + (size_t)(oc0 + mt * 16 + n) * CIN + k * 32 + quad * 8;
      float4 a = *(const float4*)wp;
      float4 c = *(const float4*)(wp + 4);
      wf[mt][k] = (bf16x8){(bf16_t)a.x, (bf16_t)a.y, (bf16_t)a.z, (bf16_t)a.w,
                           (bf16_t)c.x, (bf16_t)c.y, (bf16_t)c.z, (bf16_t)c.w};
    }

  bf16x8 bfr[4];
#pragma unroll
  for (int k = 0; k < 4; ++k)
    bfr[k] = *(const bf16x8*)(aoT + ((size_t)(b * NHEAD + k) * NPIX + p) * DHEAD + quad * 8);

  f32x4 acc[4];
#pragma unroll
  for (int mt = 0; mt < 4; ++mt) acc[mt] = (f32x4){0.f, 0.f, 0.f, 0.f};
#pragma unroll
  for (int k = 0; k < 4; ++k)
#pragma unroll
    for (int mt = 0; mt < 4; ++mt)
      acc[mt] = __builtin_amdgcn_mfma_f32_16x16x32_bf16(wf[mt][k], bfr[k], acc[mt], 0, 0, 0);

#pragma unroll
  for (int mt = 0; mt < 4; ++mt) {
    const int oc = oc0 + mt * 16 + quad * 4;
#pragma unroll
    for (int r = 0; r < 4; ++r)
      out[((size_t)b * CIN + oc + r) * NPIX + p] = acc[mt][r] + bias[oc + r];
  }
}

// ---------------------------------------------------------------------------
extern "C" void kernel_launch(void* const* d_in, const int* in_sizes, int n_in,
                              void* d_out, int out_size, void* d_ws, size_t ws_size,
                              hipStream_t stream) {
  const float* x     = (const float*)d_in[0];   // [4,128,64,64]
  const float* w_qkv = (const float*)d_in[1];   // [384,128]
  const float* w_out = (const float*)d_in[2];   // [128,128]
  const float* b_out = (const float*)d_in[3];   // [128]
  float* out = (float*)d_out;                   // [4,128,64,64]

  // ws (bytes): qb 0 | kb 4M | vT 8M | aoT 12M..16M  (16 MB total)
  char* base = (char*)d_ws;
  ushort* qb  = (ushort*)base;
  ushort* kb  = (ushort*)(base + (size_t)4 * 1024 * 1024);
  ushort* vT  = (ushort*)(base + (size_t)8 * 1024 * 1024);
  ushort* aoT = (ushort*)(base + (size_t)12 * 1024 * 1024);

  qkv_mfma<<<dim3(128, 4), 384, 0, stream>>>(x, w_qkv, qb, kb, vT);
  flash_mfma<<<dim3(1024), 256, 0, stream>>>(qb, kb, vT, aoT);
  out_mfma<<<dim3(128, 4), 256, 0, stream>>>(aoT, w_out, b_out, out);
}